// Round 1
// baseline (866.315 us; speedup 1.0000x reference)
//
#include <hip/hip_runtime.h>
#include <stdint.h>

// Window attention, Swin-style. B=4096 windows, N=49, C=256, NH=8, D=32.
// bf16 MFMA pipeline: prep(weights->bf16 B^T) -> qkv GEMM -> per-(b,h) attention -> proj GEMM.

typedef __attribute__((ext_vector_type(8))) short bf16x8;
typedef __attribute__((ext_vector_type(4))) float f32x4;

#define PARTSZ 51380224    // 4096*8*49*32, elements per q/k/v part
#define BHSTRIDE 1568      // 49*32
#define BSTRIDE 12544      // 8*49*32

__device__ __forceinline__ unsigned short f2bf(float f) {
    unsigned u = __float_as_uint(f);
    u += 0x7fffu + ((u >> 16) & 1u);   // RNE
    return (unsigned short)(u >> 16);
}
__device__ __forceinline__ unsigned pk2(float a, float b) {
    return (unsigned)f2bf(a) | ((unsigned)f2bf(b) << 16);
}
__device__ __forceinline__ void gl2lds16(const void* gptr, void* lptr) {
    __builtin_amdgcn_global_load_lds(
        (const __attribute__((address_space(1))) unsigned int*)gptr,
        (__attribute__((address_space(3))) unsigned int*)lptr, 16, 0, 0);
}

// ---- K0: weights fp32 -> bf16, transposed to [N][K] (B^T) layout ----
__global__ void k_prep(const float* __restrict__ qkv_w, const float* __restrict__ proj_w,
                       short* __restrict__ Wqkv_t, short* __restrict__ Wproj_t) {
    int tid = blockIdx.x * 256 + threadIdx.x;   // 262144 total
    if (tid < 196608) {                          // 768*256
        int nn = tid >> 8, kk = tid & 255;
        Wqkv_t[tid] = (short)f2bf(qkv_w[kk * 768 + nn]);
    } else {
        int t2 = tid - 196608;                   // 256*256
        int nn = t2 >> 8, kk = t2 & 255;
        Wproj_t[t2] = (short)f2bf(proj_w[kk * 256 + nn]);
    }
}

// ---- K1: qkv = x @ qkv_w + b, scatter to q/k/v [b][h][n][d] bf16 ----
__global__ __launch_bounds__(256) void k_gemm_qkv(const float* __restrict__ x,
        const short* __restrict__ Wt, const float* __restrict__ bias,
        short* __restrict__ qkv) {
    __shared__ __align__(16) short As[128 * 32];
    __shared__ __align__(16) short Bs[128 * 32];
    int bx = blockIdx.x;
    int nblk = bx % 6, mblk = bx / 6;
    int m0 = mblk * 128, n0 = nblk * 128;
    int t = threadIdx.x;
    int wid = t >> 6, lane = t & 63;
    int l15 = lane & 15, g = lane >> 4;
    int wr = wid >> 1, wc = wid & 1;

    f32x4 acc[4][4];
    for (int i = 0; i < 4; i++)
        for (int j = 0; j < 4; j++) acc[i][j] = (f32x4){0.f, 0.f, 0.f, 0.f};

    int arow = t >> 1, acb = (t & 1) * 16;
    const float* asrc = x + (size_t)(m0 + arow) * 256 + acb;
    short* adst = &As[arow * 32 + acb];

    for (int ks = 0; ks < 8; ks++) {
        int k0 = ks * 32;
        // A stage: fp32 -> bf16 -> LDS (16 elems/thread)
        const float4* s4 = (const float4*)(asrc + k0);
        float4 f0 = s4[0], f1 = s4[1], f2 = s4[2], f3 = s4[3];
        ((uint4*)adst)[0] = make_uint4(pk2(f0.x, f0.y), pk2(f0.z, f0.w),
                                       pk2(f1.x, f1.y), pk2(f1.z, f1.w));
        ((uint4*)adst)[1] = make_uint4(pk2(f2.x, f2.y), pk2(f2.z, f2.w),
                                       pk2(f3.x, f3.y), pk2(f3.z, f3.w));
        // B stage: async global->LDS, 16B/lane, 2 issues
        for (int i = 0; i < 2; i++) {
            int cbase = i * 256 + wid * 64;
            int c = cbase + lane;
            int brow = c >> 2, bseg = c & 3;
            gl2lds16(Wt + (size_t)(n0 + brow) * 256 + k0 + bseg * 8, &Bs[cbase * 8]);
        }
        __syncthreads();
        bf16x8 af[4], bfg[4];
        for (int it = 0; it < 4; it++)
            af[it] = *(const bf16x8*)&As[(wr * 64 + it * 16 + l15) * 32 + g * 8];
        for (int jt = 0; jt < 4; jt++)
            bfg[jt] = *(const bf16x8*)&Bs[(wc * 64 + jt * 16 + l15) * 32 + g * 8];
        for (int it = 0; it < 4; it++)
            for (int jt = 0; jt < 4; jt++)
                acc[it][jt] = __builtin_amdgcn_mfma_f32_16x16x32_bf16(
                    af[it], bfg[jt], acc[it][jt], 0, 0, 0);
        __syncthreads();
    }
    // epilogue: col j -> (part, h, d); row m -> (b, n); scatter bf16
    size_t coloff[4]; float bj[4];
    for (int jt = 0; jt < 4; jt++) {
        int j = n0 + wc * 64 + jt * 16 + l15;
        int part = j >> 8, h = (j >> 5) & 7, d = j & 31;
        coloff[jt] = (size_t)part * PARTSZ + (size_t)h * BHSTRIDE + d;
        bj[jt] = bias[j];
    }
    for (int it = 0; it < 4; it++) {
        for (int r = 0; r < 4; r++) {
            int mrow = m0 + wr * 64 + it * 16 + g * 4 + r;
            int b = mrow / 49, n = mrow - b * 49;
            size_t rowoff = (size_t)b * BSTRIDE + (size_t)n * 32;
            for (int jt = 0; jt < 4; jt++)
                qkv[coloff[jt] + rowoff] = (short)f2bf(acc[it][jt][r] + bj[jt]);
        }
    }
}

// ---- K2: attention per (b,h). S^T = K*Q^T, softmax over keys, O^T = V^T*P^T ----
__global__ __launch_bounds__(64) void k_attn(const short* __restrict__ qkv,
        const float* __restrict__ rpb, short* __restrict__ aout) {
    __shared__ __align__(16) short Qs[64 * 32];   // [n][d]
    __shared__ __align__(16) short Ks[64 * 32];   // [m][d]
    __shared__ __align__(16) short Vt[32 * 64];   // [d][m]
    __shared__ __align__(16) short Pl[64 * 64];   // [n][m] unnormalized P
    __shared__ float rb[169];
    int bh = blockIdx.x;
    int b = bh >> 3, h = bh & 7;
    int L = threadIdx.x, l15 = L & 15, g = L >> 4;
    size_t base = (size_t)(b * 8 + h) * BHSTRIDE;
    const unsigned* Qg = (const unsigned*)(qkv + base);
    const unsigned* Kg = (const unsigned*)(qkv + (size_t)PARTSZ + base);
    const unsigned* Vg = (const unsigned*)(qkv + (size_t)2 * PARTSZ + base);
    for (int e = L; e < 1024; e += 64) {     // 64x32 bf16 as 1024 dwords
        int row = e >> 4, c2 = e & 15;
        bool ok = row < 49;
        unsigned q = ok ? Qg[e] : 0u;
        unsigned k = ok ? Kg[e] : 0u;
        unsigned v = ok ? Vg[e] : 0u;
        ((unsigned*)Qs)[e] = q;
        ((unsigned*)Ks)[e] = k;
        Vt[(2 * c2) * 64 + row]     = (short)(v & 0xffffu);
        Vt[(2 * c2 + 1) * 64 + row] = (short)(v >> 16);
    }
    for (int e = L; e < 169; e += 64) rb[e] = rpb[e * 8 + h];
    __syncthreads();

    bf16x8 ka[4], qb[4];
    for (int mt = 0; mt < 4; mt++) ka[mt] = *(const bf16x8*)&Ks[(mt * 16 + l15) * 32 + g * 8];
    for (int nt = 0; nt < 4; nt++) qb[nt] = *(const bf16x8*)&Qs[(nt * 16 + l15) * 32 + g * 8];
    f32x4 zero = {0.f, 0.f, 0.f, 0.f};
    f32x4 s[4][4];
    for (int mt = 0; mt < 4; mt++)
        for (int nt = 0; nt < 4; nt++)
            s[mt][nt] = __builtin_amdgcn_mfma_f32_16x16x32_bf16(ka[mt], qb[nt], zero, 0, 0, 0);
    // s[mt][nt]: lane holds S^T[m = mt*16+g*4+r][n = nt*16+l15]

    const float scale = 0.17677669529663687f;   // 1/sqrt(32)
    int an[4];
    for (int nt = 0; nt < 4; nt++) {
        int n = nt * 16 + l15;
        int i = n / 7;
        an[nt] = 13 * i + (n - 7 * i) + 84;
    }
    int bmv[16];
    for (int mt = 0; mt < 4; mt++)
        for (int r = 0; r < 4; r++) {
            int m = mt * 16 + g * 4 + r;
            int i2 = m / 7;
            bmv[mt * 4 + r] = 13 * i2 + (m - 7 * i2);
        }
    for (int nt = 0; nt < 4; nt++)
        for (int mt = 0; mt < 4; mt++)
            for (int r = 0; r < 4; r++) {
                int m = mt * 16 + g * 4 + r;
                int idx = an[nt] - bmv[mt * 4 + r];
                idx = idx < 0 ? 0 : (idx > 168 ? 168 : idx);
                float val = s[mt][nt][r] * scale + rb[idx];
                s[mt][nt][r] = (m < 49) ? val : -1e30f;
            }
    float rsum[4];
    for (int nt = 0; nt < 4; nt++) {
        float tmax = -1e30f;
        for (int mt = 0; mt < 4; mt++)
            for (int r = 0; r < 4; r++) tmax = fmaxf(tmax, s[mt][nt][r]);
        tmax = fmaxf(tmax, __shfl_xor(tmax, 16));
        tmax = fmaxf(tmax, __shfl_xor(tmax, 32));
        float sm = 0.f;
        for (int mt = 0; mt < 4; mt++)
            for (int r = 0; r < 4; r++) {
                float e = __expf(s[mt][nt][r] - tmax);
                s[mt][nt][r] = e;
                sm += e;
            }
        sm += __shfl_xor(sm, 16);
        sm += __shfl_xor(sm, 32);
        rsum[nt] = sm;
    }
    // P (unnormalized) -> Pl[n][m] bf16
    for (int nt = 0; nt < 4; nt++)
        for (int mt = 0; mt < 4; mt++) {
            unsigned* dst = (unsigned*)&Pl[(nt * 16 + l15) * 64 + mt * 16 + g * 4];
            dst[0] = pk2(s[mt][nt][0], s[mt][nt][1]);
            dst[1] = pk2(s[mt][nt][2], s[mt][nt][3]);
        }
    __syncthreads();
    // O^T = V^T * P^T : A=V^T [d][m], B=P^T (read Pl[n][m] 8-contig in m)
    bf16x8 va[2][2], pb[4][2];
    for (int dt = 0; dt < 2; dt++)
        for (int kk = 0; kk < 2; kk++)
            va[dt][kk] = *(const bf16x8*)&Vt[(dt * 16 + l15) * 64 + kk * 32 + g * 8];
    for (int nt = 0; nt < 4; nt++)
        for (int kk = 0; kk < 2; kk++)
            pb[nt][kk] = *(const bf16x8*)&Pl[(nt * 16 + l15) * 64 + kk * 32 + g * 8];
    f32x4 o[2][4];
    for (int dt = 0; dt < 2; dt++)
        for (int nt = 0; nt < 4; nt++) {
            f32x4 a = zero;
            for (int kk = 0; kk < 2; kk++)
                a = __builtin_amdgcn_mfma_f32_16x16x32_bf16(va[dt][kk], pb[nt][kk], a, 0, 0, 0);
            o[dt][nt] = a;
        }
    // store O[n][h*32+d] bf16, normalize by 1/rowsum
    for (int nt = 0; nt < 4; nt++) {
        int n = nt * 16 + l15;
        if (n >= 49) continue;
        float inv = 1.f / rsum[nt];
        size_t ob = (size_t)(b * 49 + n) * 256 + h * 32;
        for (int dt = 0; dt < 2; dt++) {
            unsigned* dst = (unsigned*)(aout + ob + dt * 16 + g * 4);
            dst[0] = pk2(o[dt][nt][0] * inv, o[dt][nt][1] * inv);
            dst[1] = pk2(o[dt][nt][2] * inv, o[dt][nt][3] * inv);
        }
    }
}

// ---- K3: out = aout @ proj_w + proj_b (fp32 out) ----
__global__ __launch_bounds__(256) void k_gemm_proj(const short* __restrict__ A,
        const short* __restrict__ Wt, const float* __restrict__ bias,
        float* __restrict__ out) {
    __shared__ __align__(16) short As[128 * 32];
    __shared__ __align__(16) short Bs[128 * 32];
    int bx = blockIdx.x;
    int nblk = bx & 1, mblk = bx >> 1;
    int m0 = mblk * 128, n0 = nblk * 128;
    int t = threadIdx.x;
    int wid = t >> 6, lane = t & 63;
    int l15 = lane & 15, g = lane >> 4;
    int wr = wid >> 1, wc = wid & 1;

    f32x4 acc[4][4];
    for (int i = 0; i < 4; i++)
        for (int j = 0; j < 4; j++) acc[i][j] = (f32x4){0.f, 0.f, 0.f, 0.f};

    for (int ks = 0; ks < 8; ks++) {
        int k0 = ks * 32;
        for (int i = 0; i < 2; i++) {
            int cbase = i * 256 + wid * 64;
            int c = cbase + lane;
            int row = c >> 2, seg = c & 3;
            gl2lds16(A + (size_t)(m0 + row) * 256 + k0 + seg * 8, &As[cbase * 8]);
            gl2lds16(Wt + (size_t)(n0 + row) * 256 + k0 + seg * 8, &Bs[cbase * 8]);
        }
        __syncthreads();
        bf16x8 af[4], bfg[4];
        for (int it = 0; it < 4; it++)
            af[it] = *(const bf16x8*)&As[(wr * 64 + it * 16 + l15) * 32 + g * 8];
        for (int jt = 0; jt < 4; jt++)
            bfg[jt] = *(const bf16x8*)&Bs[(wc * 64 + jt * 16 + l15) * 32 + g * 8];
        for (int it = 0; it < 4; it++)
            for (int jt = 0; jt < 4; jt++)
                acc[it][jt] = __builtin_amdgcn_mfma_f32_16x16x32_bf16(
                    af[it], bfg[jt], acc[it][jt], 0, 0, 0);
        __syncthreads();
    }
    float bj[4]; int jc[4];
    for (int jt = 0; jt < 4; jt++) {
        jc[jt] = n0 + wc * 64 + jt * 16 + l15;
        bj[jt] = bias[jc[jt]];
    }
    for (int it = 0; it < 4; it++)
        for (int r = 0; r < 4; r++) {
            int mrow = m0 + wr * 64 + it * 16 + g * 4 + r;
            for (int jt = 0; jt < 4; jt++)
                out[(size_t)mrow * 256 + jc[jt]] = acc[it][jt][r] + bj[jt];
        }
}

extern "C" void kernel_launch(void* const* d_in, const int* in_sizes, int n_in,
                              void* d_out, int out_size, void* d_ws, size_t ws_size,
                              hipStream_t stream) {
    const float* x      = (const float*)d_in[0];
    const float* qkv_w  = (const float*)d_in[1];
    const float* qkv_b  = (const float*)d_in[2];
    const float* rpb    = (const float*)d_in[3];
    const float* proj_w = (const float*)d_in[4];
    const float* proj_b = (const float*)d_in[5];
    float* out = (float*)d_out;

    // ws layout (shorts): Wqkv_t[768*256] | Wproj_t[256*256] | qkv[3*PARTSZ] | aout[200704*256]
    short* Wqkv_t  = (short*)d_ws;
    short* Wproj_t = Wqkv_t + 768 * 256;
    short* qkv     = Wproj_t + 256 * 256;
    short* aout    = qkv + (size_t)3 * PARTSZ;
    if (ws_size < 411566080ull) return;  // need ~412 MB scratch

    k_prep<<<1024, 256, 0, stream>>>(qkv_w, proj_w, Wqkv_t, Wproj_t);
    k_gemm_qkv<<<9408, 256, 0, stream>>>(x, Wqkv_t, qkv_b, qkv);
    k_attn<<<32768, 64, 0, stream>>>(qkv, rpb, aout);
    k_gemm_proj<<<3136, 256, 0, stream>>>(aout, Wproj_t, proj_b, out);
}

// Round 2
// 704.362 us; speedup vs baseline: 1.2299x; 1.2299x over previous
//
#include <hip/hip_runtime.h>
#include <stdint.h>

// Window attention, Swin-style. B=4096 windows, N=49, C=256, NH=8, D=32.
// bf16 MFMA pipeline: prep(weights->bf16 B^T) -> qkv GEMM (transposed-C epilogue)
// -> per-(b,h) attention (4 waves/block, LDS-aliased) -> proj GEMM (transposed-C).

typedef __attribute__((ext_vector_type(8))) short bf16x8;
typedef __attribute__((ext_vector_type(4))) float f32x4;

#define PARTSZ 51380224    // 4096*8*49*32, elements per q/k/v part
#define BHSTRIDE 1568      // 49*32
#define BSTRIDE 12544      // 8*49*32

__device__ __forceinline__ unsigned short f2bf(float f) {
    unsigned u = __float_as_uint(f);
    u += 0x7fffu + ((u >> 16) & 1u);   // RNE
    return (unsigned short)(u >> 16);
}
__device__ __forceinline__ unsigned pk2(float a, float b) {
    return (unsigned)f2bf(a) | ((unsigned)f2bf(b) << 16);
}
__device__ __forceinline__ void gl2lds16(const void* gptr, void* lptr) {
    __builtin_amdgcn_global_load_lds(
        (const __attribute__((address_space(1))) unsigned int*)gptr,
        (__attribute__((address_space(3))) unsigned int*)lptr, 16, 0, 0);
}

// ---- K0: weights fp32 -> bf16, transposed to [N][K] (B^T) layout ----
__global__ void k_prep(const float* __restrict__ qkv_w, const float* __restrict__ proj_w,
                       short* __restrict__ Wqkv_t, short* __restrict__ Wproj_t) {
    int tid = blockIdx.x * 256 + threadIdx.x;   // 262144 total
    if (tid < 196608) {                          // 768*256
        int nn = tid >> 8, kk = tid & 255;
        Wqkv_t[tid] = (short)f2bf(qkv_w[kk * 768 + nn]);
    } else {
        int t2 = tid - 196608;                   // 256*256
        int nn = t2 >> 8, kk = t2 & 255;
        Wproj_t[t2] = (short)f2bf(proj_w[kk * 256 + nn]);
    }
}

// ---- K1: qkv^T = Wqkv^T * x^T (features = MFMA rows), scatter d-contiguous ----
__global__ __launch_bounds__(256) void k_gemm_qkv(const float* __restrict__ x,
        const short* __restrict__ Wt, const float* __restrict__ bias,
        short* __restrict__ qkv) {
    __shared__ __align__(16) short As[128 * 32];   // x tokens tile [tok][k]
    __shared__ __align__(16) short Bs[128 * 32];   // W^T tile [feat][k]
    int bx = blockIdx.x;
    int fblk = bx % 6, tblk = bx / 6;
    int F0 = fblk * 128, T0 = tblk * 128;
    int t = threadIdx.x;
    int wid = t >> 6, lane = t & 63;
    int l15 = lane & 15, g = lane >> 4;
    int wr = wid >> 1, wc = wid & 1;

    f32x4 acc[4][4];
    for (int i = 0; i < 4; i++)
        for (int j = 0; j < 4; j++) acc[i][j] = (f32x4){0.f, 0.f, 0.f, 0.f};

    int arow = t >> 1, acb = (t & 1) * 16;
    const float* asrc = x + (size_t)(T0 + arow) * 256 + acb;
    short* adst = &As[arow * 32 + acb];

    for (int ks = 0; ks < 8; ks++) {
        int k0 = ks * 32;
        // A stage: x fp32 -> bf16 -> LDS (16 elems/thread)
        const float4* s4 = (const float4*)(asrc + k0);
        float4 f0 = s4[0], f1 = s4[1], f2 = s4[2], f3 = s4[3];
        ((uint4*)adst)[0] = make_uint4(pk2(f0.x, f0.y), pk2(f0.z, f0.w),
                                       pk2(f1.x, f1.y), pk2(f1.z, f1.w));
        ((uint4*)adst)[1] = make_uint4(pk2(f2.x, f2.y), pk2(f2.z, f2.w),
                                       pk2(f3.x, f3.y), pk2(f3.z, f3.w));
        // B stage (weights): async global->LDS, 16B/lane, 2 issues
        for (int i = 0; i < 2; i++) {
            int cbase = i * 256 + wid * 64;
            int c = cbase + lane;
            int brow = c >> 2, bseg = c & 3;
            gl2lds16(Wt + (size_t)(F0 + brow) * 256 + k0 + bseg * 8, &Bs[cbase * 8]);
        }
        __syncthreads();
        bf16x8 af[4], bfg[4];
        for (int it = 0; it < 4; it++)                       // A = features
            af[it] = *(const bf16x8*)&Bs[(wr * 64 + it * 16 + l15) * 32 + g * 8];
        for (int jt = 0; jt < 4; jt++)                       // B = tokens
            bfg[jt] = *(const bf16x8*)&As[(wc * 64 + jt * 16 + l15) * 32 + g * 8];
        for (int it = 0; it < 4; it++)
            for (int jt = 0; jt < 4; jt++)
                acc[it][jt] = __builtin_amdgcn_mfma_f32_16x16x32_bf16(
                    af[it], bfg[jt], acc[it][jt], 0, 0, 0);
        __syncthreads();
    }
    // epilogue: row = feature j (4 consecutive d per lane), col = token m
    size_t tokoff[4];
    for (int jt = 0; jt < 4; jt++) {
        int m = T0 + wc * 64 + jt * 16 + l15;
        int b = m / 49, n = m - b * 49;
        tokoff[jt] = (size_t)b * BSTRIDE + (size_t)n * 32;
    }
    for (int it = 0; it < 4; it++) {
        int jr = F0 + wr * 64 + it * 16 + g * 4;
        int part = jr >> 8, hh = (jr >> 5) & 7, db = jr & 31;
        size_t ro = (size_t)part * PARTSZ + (size_t)hh * BHSTRIDE + db;
        float4 bv = *(const float4*)&bias[jr];
        for (int jt = 0; jt < 4; jt++) {
            unsigned* dst = (unsigned*)(qkv + ro + tokoff[jt]);
            dst[0] = pk2(acc[it][jt][0] + bv.x, acc[it][jt][1] + bv.y);
            dst[1] = pk2(acc[it][jt][2] + bv.z, acc[it][jt][3] + bv.w);
        }
    }
}

// ---- K2: attention per (b,h), 4 waves/block (wave = one 16-col n-block) ----
__global__ __launch_bounds__(256) void k_attn(const short* __restrict__ qkv,
        const float* __restrict__ rpb, short* __restrict__ aout) {
    // [0,4608): Pl 64x72 (aliases Qs 64x32 @0, Ks 64x32 @2048); [4608,6912): Vt 32x72
    __shared__ __align__(16) short smem[6912];
    __shared__ float rb[169];
    short* Qs = smem;
    short* Ks = smem + 2048;
    short* Pl = smem;
    short* Vt = smem + 4608;

    int bh = blockIdx.x;
    int h = bh & 7;
    int t = threadIdx.x;
    int w = t >> 6;                 // wave id == nt block
    int L = t & 63, l15 = L & 15, g = L >> 4;
    size_t base = (size_t)bh * BHSTRIDE;

    // Q,K: each wave async-stages its 1KB chunk (rows 49..63 read spill bytes; masked later)
    const char* Qg = (const char*)(qkv + base);
    const char* Kg = (const char*)(qkv + (size_t)PARTSZ + base);
    gl2lds16(Qg + w * 1024 + L * 16, Qs + w * 512);
    gl2lds16(Kg + w * 1024 + L * 16, Ks + w * 512);
    // V: thread t loads row r chunk c as uint4, writes transposed; zero pad rows
    {
        int r = t >> 2, c = t & 3;
        const uint4* Vg4 = (const uint4*)(qkv + (size_t)2 * PARTSZ + base);
        uint4 v = Vg4[r * 4 + c];
        if (r >= 49) v = make_uint4(0u, 0u, 0u, 0u);
        unsigned vv[4] = {v.x, v.y, v.z, v.w};
        int d0 = c * 8;
        for (int i = 0; i < 4; i++) {
            Vt[(d0 + 2 * i) * 72 + r]     = (short)(vv[i] & 0xffffu);
            Vt[(d0 + 2 * i + 1) * 72 + r] = (short)(vv[i] >> 16);
        }
    }
    if (t < 169) rb[t] = rpb[t * 8 + h];
    __syncthreads();

    // S^T block: rows m (keys), cols n = w*16+l15 (queries)
    bf16x8 ka[4], qb;
    for (int mt = 0; mt < 4; mt++)
        ka[mt] = *(const bf16x8*)&Ks[(mt * 16 + l15) * 32 + g * 8];
    qb = *(const bf16x8*)&Qs[(w * 16 + l15) * 32 + g * 8];
    f32x4 zero = {0.f, 0.f, 0.f, 0.f};
    f32x4 s[4];
    for (int mt = 0; mt < 4; mt++)
        s[mt] = __builtin_amdgcn_mfma_f32_16x16x32_bf16(ka[mt], qb, zero, 0, 0, 0);
    __syncthreads();   // all waves done reading Qs/Ks before Pl overwrites them

    const float scale = 0.17677669529663687f;   // 1/sqrt(32)
    int n = w * 16 + l15;
    int ni = n / 7;
    int an = 13 * ni + (n - 7 * ni) + 84;
    for (int mt = 0; mt < 4; mt++)
        for (int r = 0; r < 4; r++) {
            int m = mt * 16 + g * 4 + r;
            int mi = m / 7;
            int idx = an - (13 * mi + (m - 7 * mi));
            idx = idx < 0 ? 0 : (idx > 168 ? 168 : idx);
            float val = s[mt][r] * scale + rb[idx];
            s[mt][r] = (m < 49) ? val : -1e30f;
        }
    float tmax = -1e30f;
    for (int mt = 0; mt < 4; mt++)
        for (int r = 0; r < 4; r++) tmax = fmaxf(tmax, s[mt][r]);
    tmax = fmaxf(tmax, __shfl_xor(tmax, 16));
    tmax = fmaxf(tmax, __shfl_xor(tmax, 32));
    float rsum = 0.f;
    for (int mt = 0; mt < 4; mt++)
        for (int r = 0; r < 4; r++) {
            float e = __expf(s[mt][r] - tmax);
            s[mt][r] = e;
            rsum += e;
        }
    rsum += __shfl_xor(rsum, 16);
    rsum += __shfl_xor(rsum, 32);

    // P (unnormalized) -> Pl[n][m], stride 72
    for (int mt = 0; mt < 4; mt++) {
        unsigned* dst = (unsigned*)&Pl[(w * 16 + l15) * 72 + mt * 16 + g * 4];
        dst[0] = pk2(s[mt][0], s[mt][1]);
        dst[1] = pk2(s[mt][2], s[mt][3]);
    }
    __syncthreads();   // order Pl writes (cross-lane) before reads

    // O^T = V^T * P^T : rows d, cols n (this wave's 16 queries)
    bf16x8 va[2][2], pb[2];
    for (int dt = 0; dt < 2; dt++)
        for (int kk = 0; kk < 2; kk++)
            va[dt][kk] = *(const bf16x8*)&Vt[(dt * 16 + l15) * 72 + kk * 32 + g * 8];
    for (int kk = 0; kk < 2; kk++)
        pb[kk] = *(const bf16x8*)&Pl[(w * 16 + l15) * 72 + kk * 32 + g * 8];
    f32x4 o[2];
    for (int dt = 0; dt < 2; dt++) {
        f32x4 a = zero;
        for (int kk = 0; kk < 2; kk++)
            a = __builtin_amdgcn_mfma_f32_16x16x32_bf16(va[dt][kk], pb[kk], a, 0, 0, 0);
        o[dt] = a;
    }
    if (n < 49) {
        float inv = 1.f / rsum;
        size_t ob = (size_t)((bh >> 3) * 49 + n) * 256 + h * 32;
        for (int dt = 0; dt < 2; dt++) {
            unsigned* dst = (unsigned*)(aout + ob + dt * 16 + g * 4);
            dst[0] = pk2(o[dt][0] * inv, o[dt][1] * inv);
            dst[1] = pk2(o[dt][2] * inv, o[dt][3] * inv);
        }
    }
}

// ---- K3: out^T = Wproj^T * aout^T (features = rows), float4 stores ----
__global__ __launch_bounds__(256) void k_gemm_proj(const short* __restrict__ A,
        const short* __restrict__ Wt, const float* __restrict__ bias,
        float* __restrict__ out) {
    __shared__ __align__(16) short As[128 * 32];   // aout tokens tile
    __shared__ __align__(16) short Bs[128 * 32];   // Wproj^T tile
    int bx = blockIdx.x;
    int fblk = bx & 1, tblk = bx >> 1;
    int F0 = fblk * 128, T0 = tblk * 128;
    int t = threadIdx.x;
    int wid = t >> 6, lane = t & 63;
    int l15 = lane & 15, g = lane >> 4;
    int wr = wid >> 1, wc = wid & 1;

    f32x4 acc[4][4];
    for (int i = 0; i < 4; i++)
        for (int j = 0; j < 4; j++) acc[i][j] = (f32x4){0.f, 0.f, 0.f, 0.f};

    for (int ks = 0; ks < 8; ks++) {
        int k0 = ks * 32;
        for (int i = 0; i < 2; i++) {
            int cbase = i * 256 + wid * 64;
            int c = cbase + lane;
            int row = c >> 2, seg = c & 3;
            gl2lds16(A + (size_t)(T0 + row) * 256 + k0 + seg * 8, &As[cbase * 8]);
            gl2lds16(Wt + (size_t)(F0 + row) * 256 + k0 + seg * 8, &Bs[cbase * 8]);
        }
        __syncthreads();
        bf16x8 af[4], bfg[4];
        for (int it = 0; it < 4; it++)
            af[it] = *(const bf16x8*)&Bs[(wr * 64 + it * 16 + l15) * 32 + g * 8];
        for (int jt = 0; jt < 4; jt++)
            bfg[jt] = *(const bf16x8*)&As[(wc * 64 + jt * 16 + l15) * 32 + g * 8];
        for (int it = 0; it < 4; it++)
            for (int jt = 0; jt < 4; jt++)
                acc[it][jt] = __builtin_amdgcn_mfma_f32_16x16x32_bf16(
                    af[it], bfg[jt], acc[it][jt], 0, 0, 0);
        __syncthreads();
    }
    int mtok[4];
    for (int jt = 0; jt < 4; jt++) mtok[jt] = T0 + wc * 64 + jt * 16 + l15;
    for (int it = 0; it < 4; it++) {
        int jr = F0 + wr * 64 + it * 16 + g * 4;
        float4 bv = *(const float4*)&bias[jr];
        for (int jt = 0; jt < 4; jt++) {
            float4 val = make_float4(acc[it][jt][0] + bv.x, acc[it][jt][1] + bv.y,
                                     acc[it][jt][2] + bv.z, acc[it][jt][3] + bv.w);
            *(float4*)&out[(size_t)mtok[jt] * 256 + jr] = val;
        }
    }
}

extern "C" void kernel_launch(void* const* d_in, const int* in_sizes, int n_in,
                              void* d_out, int out_size, void* d_ws, size_t ws_size,
                              hipStream_t stream) {
    const float* x      = (const float*)d_in[0];
    const float* qkv_w  = (const float*)d_in[1];
    const float* qkv_b  = (const float*)d_in[2];
    const float* rpb    = (const float*)d_in[3];
    const float* proj_w = (const float*)d_in[4];
    const float* proj_b = (const float*)d_in[5];
    float* out = (float*)d_out;

    // ws layout (shorts): Wqkv_t[768*256] | Wproj_t[256*256] | qkv[3*PARTSZ] | aout[200704*256]
    short* Wqkv_t  = (short*)d_ws;
    short* Wproj_t = Wqkv_t + 768 * 256;
    short* qkv     = Wproj_t + 256 * 256;
    short* aout    = qkv + (size_t)3 * PARTSZ;
    if (ws_size < 411566080ull) return;  // need ~412 MB scratch

    k_prep<<<1024, 256, 0, stream>>>(qkv_w, proj_w, Wqkv_t, Wproj_t);
    k_gemm_qkv<<<9408, 256, 0, stream>>>(x, Wqkv_t, qkv_b, qkv);
    k_attn<<<32768, 256, 0, stream>>>(qkv, rpb, aout);
    k_gemm_proj<<<3136, 256, 0, stream>>>(aout, Wproj_t, proj_b, out);
}